// Round 1
// baseline (1131.752 us; speedup 1.0000x reference)
//
#include <hip/hip_runtime.h>
#include <hip/hip_bf16.h>

#define T_TOK 2048
#define HID   2048
#define NEXP  8
#define INTER 1408

typedef float f32x4 __attribute__((ext_vector_type(4)));
typedef __bf16 bf16x8 __attribute__((ext_vector_type(8)));

__device__ __forceinline__ unsigned pk(__bf16 a, __bf16 b) {
    return (unsigned)__builtin_bit_cast(unsigned short, a) |
           ((unsigned)__builtin_bit_cast(unsigned short, b) << 16);
}

// ---------------- Router: logits -> top2 -> normalized weights -> expert lists
__global__ __launch_bounds__(256)
void router_kernel(const float* __restrict__ hs, const float* __restrict__ gw,
                   int* __restrict__ cnt, int* __restrict__ list,
                   float* __restrict__ wslot)
{
    const int wv = threadIdx.x >> 6, lane = threadIdx.x & 63;
    const int t = blockIdx.x * 4 + wv;
    float acc[8];
#pragma unroll
    for (int e = 0; e < 8; ++e) acc[e] = 0.f;
    const float* xr = hs + (size_t)t * HID;
    for (int it = 0; it < HID / 256; ++it) {
        const int h = it * 256 + lane * 4;
        float4 x = *reinterpret_cast<const float4*>(xr + h);
#pragma unroll
        for (int e = 0; e < 8; ++e) {
            float4 g = *reinterpret_cast<const float4*>(gw + e * HID + h);
            acc[e] += x.x * g.x + x.y * g.y + x.z * g.z + x.w * g.w;
        }
    }
#pragma unroll
    for (int e = 0; e < 8; ++e) {
#pragma unroll
        for (int off = 32; off >= 1; off >>= 1)
            acc[e] += __shfl_xor(acc[e], off, 64);
    }
    if (lane == 0) {
        int b0 = 0, b1 = -1;
        float v0 = -1e30f, v1 = -1e30f;
#pragma unroll
        for (int e = 0; e < 8; ++e) {
            if (acc[e] > v0) { v1 = v0; b1 = b0; v0 = acc[e]; b0 = e; }
            else if (acc[e] > v1) { v1 = acc[e]; b1 = e; }
        }
        // renormalized top-2 softmax: w0 = p0/(p0+p1) = sigmoid(l0-l1)
        float w0 = 1.f / (1.f + __expf(v1 - v0));
        float w1 = 1.f - w0;
        int p0 = atomicAdd(&cnt[b0], 1);
        list[b0 * T_TOK + p0] = 2 * t;
        wslot[2 * t] = w0;
        int p1 = atomicAdd(&cnt[b1], 1);
        list[b1 * T_TOK + p1] = 2 * t + 1;
        wslot[2 * t + 1] = w1;
    }
}

// ---------------- Grouped GEMM, 128x128x(K) tile, split-bf16 MFMA (fp32 accuracy)
// MODE 0: gate   : C = X @ Wg          -> G[slot][col]
// MODE 1: up     : C = X @ Wu          -> A[slot][col] = silu(G)*C
// MODE 2: down   : C = A @ Wd          -> atomicAdd(out[token][col], C*w)
template<int MODE, int K_, int N_>
__global__ __launch_bounds__(256, 2)
void moe_gemm(const float* __restrict__ Asrc, const float* __restrict__ Ball,
              const int* __restrict__ cnt, const int* __restrict__ list,
              const float* __restrict__ wslot, const float* __restrict__ Gbuf,
              float* __restrict__ Obuf)
{
    const int e = blockIdx.z;
    const int cntE = cnt[e];
    const int rb = blockIdx.x * 128;
    if (rb >= cntE) return;
    const int nb = blockIdx.y * 128;
    const int tid = threadIdx.x;
    const int lane = tid & 63;
    const int wv = tid >> 6;
    const int wr = (wv >> 1) * 64, wc = (wv & 1) * 64;
    const int p = lane & 15, kg = lane >> 4;

    // LDS: padded rows of 40 halfwords (80B, 16B-aligned) for A; swizzled k for B
    __shared__ __align__(16) __bf16 AhL[128 * 40], AlL[128 * 40];
    __shared__ __align__(16) __bf16 BhL[128 * 40], BlL[128 * 40];
    __shared__ int slots[128];

    if (tid < 128) {
        int r = rb + tid;
        slots[tid] = (r < cntE) ? list[e * T_TOK + r] : 0;
    }
    __syncthreads();

    const float* Bsrc = Ball + (size_t)e * K_ * N_;

    f32x4 acc[4][4];
#pragma unroll
    for (int i = 0; i < 4; ++i)
#pragma unroll
        for (int j = 0; j < 4; ++j) acc[i][j] = (f32x4)0.0f;

    for (int kt = 0; kt < K_ / 32; ++kt) {
        const int kb = kt * 32;
        // ---- stage A (gathered rows), 128x32 fp32 -> hi/lo bf16
#pragma unroll
        for (int pp = 0; pp < 4; ++pp) {
            int idx = tid + pp * 256;
            int row = idx >> 3, c4 = idx & 7;
            int s = slots[row];
            size_t arow = (MODE < 2) ? (size_t)(s >> 1) * HID : (size_t)s * K_;
            float4 v = *reinterpret_cast<const float4*>(Asrc + arow + kb + c4 * 4);
            __bf16 h0 = (__bf16)v.x, h1 = (__bf16)v.y, h2 = (__bf16)v.z, h3 = (__bf16)v.w;
            uint2 hi, lo;
            hi.x = pk(h0, h1); hi.y = pk(h2, h3);
            lo.x = pk((__bf16)(v.x - (float)h0), (__bf16)(v.y - (float)h1));
            lo.y = pk((__bf16)(v.z - (float)h2), (__bf16)(v.w - (float)h3));
            int off = row * 40 + c4 * 4;
            *reinterpret_cast<uint2*>(&AhL[off]) = hi;
            *reinterpret_cast<uint2*>(&AlL[off]) = lo;
        }
        // ---- stage B with in-register transpose: thread owns 4k x 4n block
        {
            int kblk = tid >> 5, a = tid & 31;
            int k0 = kblk * 4, n0 = a * 4;
            float4 r0 = *reinterpret_cast<const float4*>(Bsrc + (size_t)(kb + k0 + 0) * N_ + nb + n0);
            float4 r1 = *reinterpret_cast<const float4*>(Bsrc + (size_t)(kb + k0 + 1) * N_ + nb + n0);
            float4 r2 = *reinterpret_cast<const float4*>(Bsrc + (size_t)(kb + k0 + 2) * N_ + nb + n0);
            float4 r3 = *reinterpret_cast<const float4*>(Bsrc + (size_t)(kb + k0 + 3) * N_ + nb + n0);
            const float* rr0 = (const float*)&r0;
            const float* rr1 = (const float*)&r1;
            const float* rr2 = (const float*)&r2;
            const float* rr3 = (const float*)&r3;
#pragma unroll
            for (int cc = 0; cc < 4; ++cc) {
                int n = n0 + cc;
                float x0 = rr0[cc], x1 = rr1[cc], x2 = rr2[cc], x3 = rr3[cc];
                __bf16 h0 = (__bf16)x0, h1 = (__bf16)x1, h2 = (__bf16)x2, h3 = (__bf16)x3;
                uint2 hi, lo;
                hi.x = pk(h0, h1); hi.y = pk(h2, h3);
                lo.x = pk((__bf16)(x0 - (float)h0), (__bf16)(x1 - (float)h1));
                lo.y = pk((__bf16)(x2 - (float)h2), (__bf16)(x3 - (float)h3));
                int kx = k0 ^ (((n >> 3) & 3) << 3);   // 8-halfword XOR swizzle (keeps b128 16B-aligned)
                int off = n * 40 + kx;
                *reinterpret_cast<uint2*>(&BhL[off]) = hi;
                *reinterpret_cast<uint2*>(&BlL[off]) = lo;
            }
        }
        __syncthreads();

        bf16x8 ah[4], al[4], bh[4], bl[4];
#pragma unroll
        for (int mi = 0; mi < 4; ++mi) {
            int off = (wr + mi * 16 + p) * 40 + kg * 8;
            ah[mi] = *reinterpret_cast<const bf16x8*>(&AhL[off]);
            al[mi] = *reinterpret_cast<const bf16x8*>(&AlL[off]);
        }
#pragma unroll
        for (int ni = 0; ni < 4; ++ni) {
            int n = wc + ni * 16 + p;
            int kx = (kg * 8) ^ (((n >> 3) & 3) << 3);
            int off = n * 40 + kx;
            bh[ni] = *reinterpret_cast<const bf16x8*>(&BhL[off]);
            bl[ni] = *reinterpret_cast<const bf16x8*>(&BlL[off]);
        }
#pragma unroll
        for (int mi = 0; mi < 4; ++mi)
#pragma unroll
            for (int ni = 0; ni < 4; ++ni) {
                acc[mi][ni] = __builtin_amdgcn_mfma_f32_16x16x32_bf16(ah[mi], bh[ni], acc[mi][ni], 0, 0, 0);
                acc[mi][ni] = __builtin_amdgcn_mfma_f32_16x16x32_bf16(ah[mi], bl[ni], acc[mi][ni], 0, 0, 0);
                acc[mi][ni] = __builtin_amdgcn_mfma_f32_16x16x32_bf16(al[mi], bh[ni], acc[mi][ni], 0, 0, 0);
            }
        __syncthreads();
    }

    // ---- epilogue. C/D layout: col = lane&15, row = (lane>>4)*4 + j  [m89-verified]
#pragma unroll
    for (int mi = 0; mi < 4; ++mi) {
#pragma unroll
        for (int j = 0; j < 4; ++j) {
            int lr = wr + mi * 16 + kg * 4 + j;
            int gr = rb + lr;
            if (gr < cntE) {
                int s = slots[lr];
#pragma unroll
                for (int ni = 0; ni < 4; ++ni) {
                    int col = nb + wc + ni * 16 + p;
                    float v = acc[mi][ni][j];
                    if (MODE == 0) {
                        Obuf[(size_t)s * N_ + col] = v;
                    } else if (MODE == 1) {
                        float g = Gbuf[(size_t)s * N_ + col];
                        float a = g / (1.f + __expf(-g));   // silu(g)
                        Obuf[(size_t)s * N_ + col] = a * v;
                    } else {
                        float w = wslot[s];
                        atomicAdd(&Obuf[(size_t)(s >> 1) * N_ + col], v * w);
                    }
                }
            }
        }
    }
}

extern "C" void kernel_launch(void* const* d_in, const int* in_sizes, int n_in,
                              void* d_out, int out_size, void* d_ws, size_t ws_size,
                              hipStream_t stream)
{
    const float* hs = (const float*)d_in[0];
    const float* gw = (const float*)d_in[1];
    const float* wg = (const float*)d_in[2];
    const float* wu = (const float*)d_in[3];
    const float* wd = (const float*)d_in[4];
    float* out = (float*)d_out;

    char* ws = (char*)d_ws;
    int*   cnt   = (int*)(ws);                       // 32 B
    int*   list  = (int*)(ws + 256);                 // 8*2048*4 = 64 KiB
    float* wslot = (float*)(ws + 256 + 65536);       // 16 KiB
    float* G     = (float*)(ws + (1 << 20));                         // 4096*1408 f32 = 22 MiB
    float* A     = (float*)(ws + (1 << 20) + (size_t)23068672);      // 4096*1408 f32 = 22 MiB

    hipMemsetAsync(cnt, 0, 8 * sizeof(int), stream);
    hipMemsetAsync(out, 0, (size_t)out_size * sizeof(float), stream);

    router_kernel<<<T_TOK / 4, 256, 0, stream>>>(hs, gw, cnt, list, wslot);

    // gate: X[4096x2048] @ Wg[e][2048x1408] -> G
    moe_gemm<0, 2048, 1408><<<dim3(16, 11, 8), 256, 0, stream>>>(hs, wg, cnt, list, wslot, nullptr, G);
    // up:   X @ Wu -> A = silu(G)*U
    moe_gemm<1, 2048, 1408><<<dim3(16, 11, 8), 256, 0, stream>>>(hs, wu, cnt, list, wslot, G, A);
    // down: A[4096x1408] @ Wd[e][1408x2048] -> out += w * Y   (atomic combine)
    moe_gemm<2, 1408, 2048><<<dim3(16, 16, 8), 256, 0, stream>>>(A, wd, cnt, list, wslot, nullptr, out);
}